// Round 8
// baseline (2424.920 us; speedup 1.0000x reference)
//
#include <hip/hip_runtime.h>

#define N_NODES 100000
#define N_EDGES 3200000
#define IN_F 256
#define OUT_F 128

#define ROWS_PER_BUCKET 64
#define NBIN 1563         // ceil(100000/64); bin = row >> 6
#define NBC  512          // coarse pass blocks
#define CHUNK 6272        // edges per coarse block, multiple of 4 (int4 loads)
#define GEMM_BLOCKS 782   // (N_NODES + 127) / 128

typedef __attribute__((ext_vector_type(8))) short bf16x8;
typedef __attribute__((ext_vector_type(4))) float f32x4;

union U4BF { uint4 u; bf16x8 v; };

__device__ inline unsigned short f2bf(float f) {
    union { float f; unsigned u; } v; v.f = f;
    unsigned r = v.u + 0x7FFFu + ((v.u >> 16) & 1u);   // round-to-nearest-even
    return (unsigned short)(r >> 16);
}
__device__ inline unsigned pk2(float a, float b) {
    return (unsigned)f2bf(a) | ((unsigned)f2bf(b) << 16);
}

// -------------------- Kernel 0: w -> frag-ordered bf16 --------------------
// elem e of uint4 tid: k = (tid>>9)*32 + ((tid&63)>>4)*8 + e, c = ((tid>>6)&7)*16 + (tid&15)
__global__ __launch_bounds__(256) void conv_w_kernel(
    const float* __restrict__ w, uint4* __restrict__ wbfF)
{
    int tid = blockIdx.x * 256 + threadIdx.x;   // 0..4095
    int ks = tid >> 9;
    int fn = (tid >> 6) & 7;
    int l  = tid & 63;
    int c  = fn * 16 + (l & 15);
    int k0 = ks * 32 + (l >> 4) * 8;
    const float* wp = w + (size_t)k0 * OUT_F + c;
    uint4 u;
    u.x = pk2(wp[0 * OUT_F], wp[1 * OUT_F]);
    u.y = pk2(wp[2 * OUT_F], wp[3 * OUT_F]);
    u.z = pk2(wp[4 * OUT_F], wp[5 * OUT_F]);
    u.w = pk2(wp[6 * OUT_F], wp[7 * OUT_F]);
    wbfF[tid] = u;
}

// -------------------- Kernel 1: fused GEMM (blocks 0..781) + coarse hist (782..1293) ----
__global__ __launch_bounds__(256) void gemm_hist_kernel(
    const float* __restrict__ x, const uint4* __restrict__ wbfF,
    unsigned short* __restrict__ h,
    const int* __restrict__ erow, int* __restrict__ cntmat)
{
    __shared__ __align__(16) char smem[65536];
    const int t = threadIdx.x;

    if (blockIdx.x < GEMM_BLOCKS) {
        // ================= GEMM path (identical to r7 v2) =================
        uint4* bsh = (uint4*)smem;
        const int lane = t & 63;
        const int wid  = t >> 6;
        const int brow = blockIdx.x * 128;
        const int ln   = lane & 15;
        const int kb   = lane >> 4;

#pragma unroll
        for (int i = 0; i < 16; ++i) bsh[i * 256 + t] = wbfF[i * 256 + t];

        int r0 = brow + wid * 32 + ln;
        int r1 = r0 + 16;
        const float* a0p = x + (size_t)(r0 < N_NODES ? r0 : N_NODES - 1) * IN_F;
        const float* a1p = x + (size_t)(r1 < N_NODES ? r1 : N_NODES - 1) * IN_F;

        f32x4 acc[2][8] = {};
        __syncthreads();

#pragma unroll
        for (int ks = 0; ks < 8; ++ks) {
            const int k = ks * 32 + kb * 8;
            U4BF a0, a1;
            {
                float4 p = *(const float4*)(a0p + k);
                float4 q = *(const float4*)(a0p + k + 4);
                a0.u.x = pk2(p.x, p.y); a0.u.y = pk2(p.z, p.w);
                a0.u.z = pk2(q.x, q.y); a0.u.w = pk2(q.z, q.w);
            }
            {
                float4 p = *(const float4*)(a1p + k);
                float4 q = *(const float4*)(a1p + k + 4);
                a1.u.x = pk2(p.x, p.y); a1.u.y = pk2(p.z, p.w);
                a1.u.z = pk2(q.x, q.y); a1.u.w = pk2(q.z, q.w);
            }
            U4BF b[8];
#pragma unroll
            for (int fn = 0; fn < 8; ++fn)
                b[fn].u = bsh[(ks * 8 + fn) * 64 + lane];
#pragma unroll
            for (int fn = 0; fn < 8; ++fn) {
                acc[0][fn] = __builtin_amdgcn_mfma_f32_16x16x32_bf16(
                    a0.v, b[fn].v, acc[0][fn], 0, 0, 0);
                acc[1][fn] = __builtin_amdgcn_mfma_f32_16x16x32_bf16(
                    a1.v, b[fn].v, acc[1][fn], 0, 0, 0);
            }
        }

#pragma unroll
        for (int fm = 0; fm < 2; ++fm) {
#pragma unroll
            for (int r = 0; r < 4; ++r) {
                int grow = brow + wid * 32 + fm * 16 + (lane >> 4) * 4 + r;
                if (grow < N_NODES) {
                    unsigned short* dst = h + (size_t)grow * OUT_F + ln;
#pragma unroll
                    for (int fn = 0; fn < 8; ++fn)
                        dst[fn * 16] = f2bf(acc[fm][fn][r]);
                }
            }
        }
    } else {
        // ================= Pass A path: coarse LDS histogram =================
        int* lhist = (int*)smem;
        const int b = blockIdx.x - GEMM_BLOCKS;
        for (int i = t; i < NBIN; i += 256) lhist[i] = 0;
        __syncthreads();

        const int base = b * CHUNK;
        const int end  = min(base + CHUNK, N_EDGES);
        for (int i = base + t * 4; i < end; i += 1024) {
            int4 r = *(const int4*)(erow + i);
            atomicAdd(&lhist[r.x >> 6], 1);
            atomicAdd(&lhist[r.y >> 6], 1);
            atomicAdd(&lhist[r.z >> 6], 1);
            atomicAdd(&lhist[r.w >> 6], 1);
        }
        __syncthreads();

        int* dst = cntmat + (size_t)b * NBIN;
        for (int j = t; j < NBIN; j += 256) dst[j] = lhist[j];
    }
}

// -------------------- Pass B: per-bin exclusive scan over 512 blocks --------------------
__global__ __launch_bounds__(256) void pass_b_kernel(
    const int* __restrict__ cntmat, int* __restrict__ blockbase,
    int* __restrict__ tot)
{
    __shared__ int sh[256];
    const int t = threadIdx.x;
    const int j = blockIdx.x;
    const int b0 = 2 * t, b1 = 2 * t + 1;
    int c0 = cntmat[(size_t)b0 * NBIN + j];
    int c1 = cntmat[(size_t)b1 * NBIN + j];
    int ps = c0 + c1;
    sh[t] = ps;
    __syncthreads();
    for (int off = 1; off < 256; off <<= 1) {
        int add = (t >= off) ? sh[t - off] : 0;
        __syncthreads();
        sh[t] += add;
        __syncthreads();
    }
    int excl = sh[t] - ps;
    blockbase[(size_t)b0 * NBIN + j] = excl;
    blockbase[(size_t)b1 * NBIN + j] = excl + c0;
    if (t == 255) tot[j] = sh[255];
}

// -------------------- Pass B2: exclusive scan of bucket totals (1563) --------------------
__global__ __launch_bounds__(1024) void pass_b2_kernel(
    const int* __restrict__ tot, int* __restrict__ bucket_base)
{
    __shared__ int sh[1024];
    const int t = threadIdx.x;
    const int i0 = 2 * t, i1 = 2 * t + 1;
    int v0 = (i0 < NBIN) ? tot[i0] : 0;
    int v1 = (i1 < NBIN) ? tot[i1] : 0;
    int ps = v0 + v1;
    sh[t] = ps;
    __syncthreads();
    for (int off = 1; off < 1024; off <<= 1) {
        int add = (t >= off) ? sh[t - off] : 0;
        __syncthreads();
        sh[t] += add;
        __syncthreads();
    }
    int excl = sh[t] - ps;
    if (i0 <= NBIN) bucket_base[i0] = excl;          // includes sentinel coverage
    if (i1 <= NBIN) bucket_base[i1] = excl + v0;     // i1==NBIN -> total = N_EDGES
}

// -------------------- Pass C: scatter edges into 64-row buckets --------------------
__global__ __launch_bounds__(256) void pass_c_kernel(
    const int* __restrict__ erow, const int* __restrict__ ecol,
    const float* __restrict__ eval_, const int* __restrict__ blockbase,
    const int* __restrict__ bucket_base, int2* __restrict__ tmp)
{
    __shared__ int cur[NBIN];
    const int t = threadIdx.x;
    const int b = blockIdx.x;
    for (int j = t; j < NBIN; j += 256)
        cur[j] = bucket_base[j] + blockbase[(size_t)b * NBIN + j];
    __syncthreads();

    const int base = b * CHUNK;
    const int end  = min(base + CHUNK, N_EDGES);
    for (int i = base + t * 4; i < end; i += 1024) {
        int4   r = *(const int4*)(erow + i);
        int4   c = *(const int4*)(ecol + i);
        float4 v = *(const float4*)(eval_ + i);
        int p0 = atomicAdd(&cur[r.x >> 6], 1);
        tmp[p0] = make_int2(c.x | ((r.x & 63) << 17), __float_as_int(v.x));
        int p1 = atomicAdd(&cur[r.y >> 6], 1);
        tmp[p1] = make_int2(c.y | ((r.y & 63) << 17), __float_as_int(v.y));
        int p2 = atomicAdd(&cur[r.z >> 6], 1);
        tmp[p2] = make_int2(c.z | ((r.z & 63) << 17), __float_as_int(v.z));
        int p3 = atomicAdd(&cur[r.w >> 6], 1);
        tmp[p3] = make_int2(c.w | ((r.w & 63) << 17), __float_as_int(v.w));
    }
}

// -------------------- fusedD: per-bucket gather + LDS accumulate + bias + out ----
// One block per 64-row bucket. 512 thr = 8 waves; wave handles 8-edge stripes.
// Lane owns feats {2*lane, 2*lane+1}; accumulate via LDS f32 atomics.
__global__ __launch_bounds__(512) void fused_d_kernel(
    const int2* __restrict__ tmp, const int* __restrict__ bucket_base,
    const unsigned* __restrict__ h2, const float* __restrict__ bias,
    float* __restrict__ out)
{
    __shared__ float acc[ROWS_PER_BUCKET * 128];   // 32 KiB
    const int t    = threadIdx.x;
    const int lane = t & 63;
    const int w    = t >> 6;                        // wave 0..7
    const int j    = blockIdx.x;
    const int base = bucket_base[j];
    const int end  = bucket_base[j + 1];

    // zero accumulator: 8192 float4 / 512 thr = 4 each
#pragma unroll
    for (int i = 0; i < 4; ++i)
        *(float4*)&acc[(i * 512 + t) * 4] = make_float4(0.f, 0.f, 0.f, 0.f);
    __syncthreads();

    int e0 = base + w * 8;
    for (; e0 + 8 <= end; e0 += 64) {
        int2 p[8];
#pragma unroll
        for (int u = 0; u < 8; ++u) p[u] = tmp[e0 + u];
        unsigned hv[8];
#pragma unroll
        for (int u = 0; u < 8; ++u)
            hv[u] = h2[((size_t)(p[u].x & 0x1FFFF) << 6) + lane];
#pragma unroll
        for (int u = 0; u < 8; ++u) {
            float v = __int_as_float(p[u].y);
            float* a = &acc[(p[u].x >> 17) * 128 + 2 * lane];
#if defined(__HIP_DEVICE_COMPILE__)
            unsafeAtomicAdd(a,     v * __uint_as_float(hv[u] << 16));
            unsafeAtomicAdd(a + 1, v * __uint_as_float(hv[u] & 0xFFFF0000u));
#else
            atomicAdd(a,     v * __uint_as_float(hv[u] << 16));
            atomicAdd(a + 1, v * __uint_as_float(hv[u] & 0xFFFF0000u));
#endif
        }
    }
    // tail (wave-uniform guard, <8 edges)
    for (; e0 < end; ++e0) {
        int2 p = tmp[e0];
        unsigned hv = h2[((size_t)(p.x & 0x1FFFF) << 6) + lane];
        float v = __int_as_float(p.y);
        float* a = &acc[(p.x >> 17) * 128 + 2 * lane];
#if defined(__HIP_DEVICE_COMPILE__)
        unsafeAtomicAdd(a,     v * __uint_as_float(hv << 16));
        unsafeAtomicAdd(a + 1, v * __uint_as_float(hv & 0xFFFF0000u));
#else
        atomicAdd(a,     v * __uint_as_float(hv << 16));
        atomicAdd(a + 1, v * __uint_as_float(hv & 0xFFFF0000u));
#endif
    }
    __syncthreads();

    // write out + bias: 64 rows x 32 float4 = 2048 / 512 thr = 4 each
    const int rbase = j * ROWS_PER_BUCKET;
#pragma unroll
    for (int i = 0; i < 4; ++i) {
        int idx = i * 512 + t;
        int rr  = idx >> 5;
        int c4  = idx & 31;
        int r   = rbase + rr;
        if (r < N_NODES) {
            float4 a = *(float4*)&acc[rr * 128 + c4 * 4];
            float4 b = ((const float4*)bias)[c4];
            *(float4*)&out[(size_t)r * OUT_F + c4 * 4] =
                make_float4(a.x + b.x, a.y + b.y, a.z + b.z, a.w + b.w);
        }
    }
}

// -------------------- launch --------------------
extern "C" void kernel_launch(void* const* d_in, const int* in_sizes, int n_in,
                              void* d_out, int out_size, void* d_ws, size_t ws_size,
                              hipStream_t stream)
{
    const float* x     = (const float*)d_in[0];
    const int*   erow  = (const int*)d_in[1];
    const int*   ecol  = (const int*)d_in[2];
    const float* eval_ = (const float*)d_in[3];
    const float* w     = (const float*)d_in[4];
    const float* bias  = (const float*)d_in[5];
    float*       out   = (float*)d_out;

    // workspace layout (bytes):
    //   h (bf16):    0          .. 25,600,000
    //   tmp:         25,600,000 .. +25,600,000  -> 51,200,000
    //   cntmat:      51,200,000 .. +3,201,024   -> 54,401,024   (512 x 1563 int)
    //   blockbase:   54,401,024 .. +3,201,024   -> 57,602,048
    //   tot:         57,602,048 .. +8,192       -> 57,610,240
    //   bucket_base: 57,610,240 .. +8,192       -> 57,618,432   (1564 int)
    //   wbfF:        57,618,432 .. +65,536      -> 57,683,968   (~57.7 MB)
    char* ws = (char*)d_ws;
    unsigned short* h           = (unsigned short*)(ws);
    int2*           tmp         = (int2*)(ws + 25600000);
    int*            cntmat      = (int*)(ws + 51200000);
    int*            blockbase   = (int*)(ws + 54401024);
    int*            tot         = (int*)(ws + 57602048);
    int*            bucket_base = (int*)(ws + 57610240);
    uint4*          wbfF        = (uint4*)(ws + 57618432);

    // 0) w -> frag-ordered bf16
    hipLaunchKernelGGL(conv_w_kernel, dim3(16), dim3(256), 0, stream, w, wbfF);

    // 1) fused: h = bf16(x@w) via MFMA  ||  coarse histogram
    hipLaunchKernelGGL(gemm_hist_kernel, dim3(GEMM_BLOCKS + NBC), dim3(256), 0, stream,
                       x, wbfF, h, erow, cntmat);

    // 2) scans
    hipLaunchKernelGGL(pass_b_kernel, dim3(NBIN), dim3(256), 0, stream,
                       cntmat, blockbase, tot);
    hipLaunchKernelGGL(pass_b2_kernel, dim3(1), dim3(1024), 0, stream, tot, bucket_base);

    // 3) scatter into bucket-ordered tmp
    hipLaunchKernelGGL(pass_c_kernel, dim3(NBC), dim3(256), 0, stream,
                       erow, ecol, eval_, blockbase, bucket_base, tmp);

    // 4) fused gather + LDS accumulate + bias
    hipLaunchKernelGGL(fused_d_kernel, dim3(NBIN), dim3(512), 0, stream,
                       tmp, bucket_base, (const unsigned*)h, bias, out);
}

// Round 9
// 237.218 us; speedup vs baseline: 10.2223x; 10.2223x over previous
//
#include <hip/hip_runtime.h>

#define N_NODES 100000
#define N_EDGES 3200000
#define IN_F 256
#define OUT_F 128

#define NBIN 391          // coarse bins: row >> 8  (99999>>8 = 390)
#define NBC  512          // coarse pass blocks
#define CHUNK 6272        // edges per coarse block, multiple of 4 (int4 loads)
#define GEMM_BLOCKS 782   // (N_NODES + 127) / 128

typedef __attribute__((ext_vector_type(8))) short bf16x8;
typedef __attribute__((ext_vector_type(4))) float f32x4;

union U4BF { uint4 u; bf16x8 v; };

__device__ inline unsigned short f2bf(float f) {
    union { float f; unsigned u; } v; v.f = f;
    unsigned r = v.u + 0x7FFFu + ((v.u >> 16) & 1u);   // round-to-nearest-even
    return (unsigned short)(r >> 16);
}
__device__ inline unsigned pk2(float a, float b) {
    return (unsigned)f2bf(a) | ((unsigned)f2bf(b) << 16);
}

// -------------------- Kernel 0: w -> frag-ordered bf16 --------------------
__global__ __launch_bounds__(256) void conv_w_kernel(
    const float* __restrict__ w, uint4* __restrict__ wbfF)
{
    int tid = blockIdx.x * 256 + threadIdx.x;   // 0..4095
    int ks = tid >> 9;
    int fn = (tid >> 6) & 7;
    int l  = tid & 63;
    int c  = fn * 16 + (l & 15);
    int k0 = ks * 32 + (l >> 4) * 8;
    const float* wp = w + (size_t)k0 * OUT_F + c;
    uint4 u;
    u.x = pk2(wp[0 * OUT_F], wp[1 * OUT_F]);
    u.y = pk2(wp[2 * OUT_F], wp[3 * OUT_F]);
    u.z = pk2(wp[4 * OUT_F], wp[5 * OUT_F]);
    u.w = pk2(wp[6 * OUT_F], wp[7 * OUT_F]);
    wbfF[tid] = u;
}

// -------------------- Kernel 1: fused GEMM (blocks 0..781) + coarse hist (782..1293) ----
__global__ __launch_bounds__(256) void gemm_hist_kernel(
    const float* __restrict__ x, const uint4* __restrict__ wbfF,
    unsigned short* __restrict__ h,
    const int* __restrict__ erow, int* __restrict__ cntmat)
{
    __shared__ __align__(16) char smem[65536];
    const int t = threadIdx.x;

    if (blockIdx.x < GEMM_BLOCKS) {
        // ================= GEMM path (r7 v2, proven) =================
        uint4* bsh = (uint4*)smem;
        const int lane = t & 63;
        const int wid  = t >> 6;
        const int brow = blockIdx.x * 128;
        const int ln   = lane & 15;
        const int kb   = lane >> 4;

#pragma unroll
        for (int i = 0; i < 16; ++i) bsh[i * 256 + t] = wbfF[i * 256 + t];

        int r0 = brow + wid * 32 + ln;
        int r1 = r0 + 16;
        const float* a0p = x + (size_t)(r0 < N_NODES ? r0 : N_NODES - 1) * IN_F;
        const float* a1p = x + (size_t)(r1 < N_NODES ? r1 : N_NODES - 1) * IN_F;

        f32x4 acc[2][8] = {};
        __syncthreads();

#pragma unroll
        for (int ks = 0; ks < 8; ++ks) {
            const int k = ks * 32 + kb * 8;
            U4BF a0, a1;
            {
                float4 p = *(const float4*)(a0p + k);
                float4 q = *(const float4*)(a0p + k + 4);
                a0.u.x = pk2(p.x, p.y); a0.u.y = pk2(p.z, p.w);
                a0.u.z = pk2(q.x, q.y); a0.u.w = pk2(q.z, q.w);
            }
            {
                float4 p = *(const float4*)(a1p + k);
                float4 q = *(const float4*)(a1p + k + 4);
                a1.u.x = pk2(p.x, p.y); a1.u.y = pk2(p.z, p.w);
                a1.u.z = pk2(q.x, q.y); a1.u.w = pk2(q.z, q.w);
            }
            U4BF b[8];
#pragma unroll
            for (int fn = 0; fn < 8; ++fn)
                b[fn].u = bsh[(ks * 8 + fn) * 64 + lane];
#pragma unroll
            for (int fn = 0; fn < 8; ++fn) {
                acc[0][fn] = __builtin_amdgcn_mfma_f32_16x16x32_bf16(
                    a0.v, b[fn].v, acc[0][fn], 0, 0, 0);
                acc[1][fn] = __builtin_amdgcn_mfma_f32_16x16x32_bf16(
                    a1.v, b[fn].v, acc[1][fn], 0, 0, 0);
            }
        }

#pragma unroll
        for (int fm = 0; fm < 2; ++fm) {
#pragma unroll
            for (int r = 0; r < 4; ++r) {
                int grow = brow + wid * 32 + fm * 16 + (lane >> 4) * 4 + r;
                if (grow < N_NODES) {
                    unsigned short* dst = h + (size_t)grow * OUT_F + ln;
#pragma unroll
                    for (int fn = 0; fn < 8; ++fn)
                        dst[fn * 16] = f2bf(acc[fm][fn][r]);
                }
            }
        }
    } else {
        // ================= Pass A path: coarse LDS histogram =================
        int* lhist = (int*)smem;
        const int b = blockIdx.x - GEMM_BLOCKS;
        for (int i = t; i < NBIN; i += 256) lhist[i] = 0;
        __syncthreads();

        const int base = b * CHUNK;
        const int end  = min(base + CHUNK, N_EDGES);
        for (int i = base + t * 4; i < end; i += 1024) {
            int4 r = *(const int4*)(erow + i);
            atomicAdd(&lhist[r.x >> 8], 1);
            atomicAdd(&lhist[r.y >> 8], 1);
            atomicAdd(&lhist[r.z >> 8], 1);
            atomicAdd(&lhist[r.w >> 8], 1);
        }
        __syncthreads();

        int* dst = cntmat + (size_t)b * NBIN;
        for (int j = t; j < NBIN; j += 256) dst[j] = lhist[j];
    }
}

// -------------------- Pass B: per-bin exclusive scan over 512 blocks --------------------
__global__ __launch_bounds__(256) void pass_b_kernel(
    const int* __restrict__ cntmat, int* __restrict__ blockbase,
    int* __restrict__ tot)
{
    __shared__ int sh[256];
    const int t = threadIdx.x;
    const int j = blockIdx.x;
    const int b0 = 2 * t, b1 = 2 * t + 1;
    int c0 = cntmat[(size_t)b0 * NBIN + j];
    int c1 = cntmat[(size_t)b1 * NBIN + j];
    int ps = c0 + c1;
    sh[t] = ps;
    __syncthreads();
    for (int off = 1; off < 256; off <<= 1) {
        int add = (t >= off) ? sh[t - off] : 0;
        __syncthreads();
        sh[t] += add;
        __syncthreads();
    }
    int excl = sh[t] - ps;
    blockbase[(size_t)b0 * NBIN + j] = excl;
    blockbase[(size_t)b1 * NBIN + j] = excl + c0;
    if (t == 255) tot[j] = sh[255];
}

// -------------------- Pass B2: exclusive scan of bucket totals --------------------
__global__ __launch_bounds__(512) void pass_b2_kernel(
    const int* __restrict__ tot, int* __restrict__ bucket_base)
{
    __shared__ int sh[512];
    const int t = threadIdx.x;
    int v = (t < NBIN) ? tot[t] : 0;
    sh[t] = v;
    __syncthreads();
    for (int off = 1; off < 512; off <<= 1) {
        int add = (t >= off) ? sh[t - off] : 0;
        __syncthreads();
        sh[t] += add;
        __syncthreads();
    }
    if (t < NBIN + 1) bucket_base[t] = sh[t] - v;   // exclusive; [NBIN] = N_EDGES
}

// -------------------- Pass C: scatter edges into coarse buckets --------------------
__global__ __launch_bounds__(256) void pass_c_kernel(
    const int* __restrict__ erow, const int* __restrict__ ecol,
    const float* __restrict__ eval_, const int* __restrict__ blockbase,
    const int* __restrict__ bucket_base, int2* __restrict__ tmp)
{
    __shared__ int cur[NBIN];
    const int t = threadIdx.x;
    const int b = blockIdx.x;
    for (int j = t; j < NBIN; j += 256)
        cur[j] = bucket_base[j] + blockbase[(size_t)b * NBIN + j];
    __syncthreads();

    const int base = b * CHUNK;
    const int end  = min(base + CHUNK, N_EDGES);
    for (int i = base + t * 4; i < end; i += 1024) {
        int4   r = *(const int4*)(erow + i);
        int4   c = *(const int4*)(ecol + i);
        float4 v = *(const float4*)(eval_ + i);
        int p0 = atomicAdd(&cur[r.x >> 8], 1);
        tmp[p0] = make_int2(c.x | ((r.x & 255) << 17), __float_as_int(v.x));
        int p1 = atomicAdd(&cur[r.y >> 8], 1);
        tmp[p1] = make_int2(c.y | ((r.y & 255) << 17), __float_as_int(v.y));
        int p2 = atomicAdd(&cur[r.z >> 8], 1);
        tmp[p2] = make_int2(c.z | ((r.z & 255) << 17), __float_as_int(v.z));
        int p3 = atomicAdd(&cur[r.w >> 8], 1);
        tmp[p3] = make_int2(c.w | ((r.w & 255) << 17), __float_as_int(v.w));
    }
}

// -------------------- Pass D: fine sort within bucket -> CSR + row_start/rowtot ----
__global__ __launch_bounds__(256) void pass_d_kernel(
    const int2* __restrict__ tmp, const int* __restrict__ bucket_base,
    int2* __restrict__ packed, int* __restrict__ row_start,
    int* __restrict__ rowtot)
{
    __shared__ int hist[256];
    __shared__ int cursor[256];
    const int t = threadIdx.x;
    const int j = blockIdx.x;
    const int base = bucket_base[j];
    const int end  = bucket_base[j + 1];

    hist[t] = 0;
    __syncthreads();

    for (int i = base + t; i < end; i += 256)
        atomicAdd(&hist[tmp[i].x >> 17], 1);
    __syncthreads();

    int hv = hist[t];
    cursor[t] = hv;
    __syncthreads();
    for (int off = 1; off < 256; off <<= 1) {
        int add = (t >= off) ? cursor[t - off] : 0;
        __syncthreads();
        cursor[t] += add;
        __syncthreads();
    }
    int excl = cursor[t] - hv;

    int r = j * 256 + t;
    if (r < N_NODES) {
        row_start[r] = base + excl;
        rowtot[r]    = hv;
    }
    __syncthreads();
    cursor[t] = excl;
    __syncthreads();

    for (int i = base + t; i < end; i += 256) {
        int2 p = tmp[i];
        int rl = p.x >> 17;
        int pos = atomicAdd(&cursor[rl], 1);
        packed[base + pos] = make_int2(p.x & 0x1FFFF, p.y);
    }
}

// -------------------- Kernel 5: per-row gather-aggregate + bias --------------------
__global__ __launch_bounds__(256) void aggregate_kernel(
    const int2* __restrict__ packed, const int* __restrict__ row_start,
    const int* __restrict__ rowtot, const unsigned* __restrict__ h2,
    const float* __restrict__ bias, float* __restrict__ out)
{
    int wave = (blockIdx.x * 256 + threadIdx.x) >> 6;
    int lane = threadIdx.x & 63;
    if (wave >= N_NODES) return;

    int start = __builtin_amdgcn_readfirstlane(row_start[wave]);
    int deg   = __builtin_amdgcn_readfirstlane(rowtot[wave]);
    int end   = start + deg;

    const unsigned* hb = h2 + lane;
    float ax = 0.f, ay = 0.f;

    int e = start;
    for (; e + 7 < end; e += 8) {
        int2 p0 = packed[e];
        int2 p1 = packed[e + 1];
        int2 p2 = packed[e + 2];
        int2 p3 = packed[e + 3];
        int2 p4 = packed[e + 4];
        int2 p5 = packed[e + 5];
        int2 p6 = packed[e + 6];
        int2 p7 = packed[e + 7];
        unsigned u0 = hb[(size_t)p0.x << 6];
        unsigned u1 = hb[(size_t)p1.x << 6];
        unsigned u2 = hb[(size_t)p2.x << 6];
        unsigned u3 = hb[(size_t)p3.x << 6];
        unsigned u4 = hb[(size_t)p4.x << 6];
        unsigned u5 = hb[(size_t)p5.x << 6];
        unsigned u6 = hb[(size_t)p6.x << 6];
        unsigned u7 = hb[(size_t)p7.x << 6];
        float v0 = __int_as_float(p0.y), v1 = __int_as_float(p1.y);
        float v2 = __int_as_float(p2.y), v3 = __int_as_float(p3.y);
        float v4 = __int_as_float(p4.y), v5 = __int_as_float(p5.y);
        float v6 = __int_as_float(p6.y), v7 = __int_as_float(p7.y);
        ax = fmaf(v0, __uint_as_float(u0 << 16), ax);
        ay = fmaf(v0, __uint_as_float(u0 & 0xFFFF0000u), ay);
        ax = fmaf(v1, __uint_as_float(u1 << 16), ax);
        ay = fmaf(v1, __uint_as_float(u1 & 0xFFFF0000u), ay);
        ax = fmaf(v2, __uint_as_float(u2 << 16), ax);
        ay = fmaf(v2, __uint_as_float(u2 & 0xFFFF0000u), ay);
        ax = fmaf(v3, __uint_as_float(u3 << 16), ax);
        ay = fmaf(v3, __uint_as_float(u3 & 0xFFFF0000u), ay);
        ax = fmaf(v4, __uint_as_float(u4 << 16), ax);
        ay = fmaf(v4, __uint_as_float(u4 & 0xFFFF0000u), ay);
        ax = fmaf(v5, __uint_as_float(u5 << 16), ax);
        ay = fmaf(v5, __uint_as_float(u5 & 0xFFFF0000u), ay);
        ax = fmaf(v6, __uint_as_float(u6 << 16), ax);
        ay = fmaf(v6, __uint_as_float(u6 & 0xFFFF0000u), ay);
        ax = fmaf(v7, __uint_as_float(u7 << 16), ax);
        ay = fmaf(v7, __uint_as_float(u7 & 0xFFFF0000u), ay);
    }
    for (; e < end; ++e) {
        int2 p0 = packed[e];
        unsigned u0 = hb[(size_t)p0.x << 6];
        float v0 = __int_as_float(p0.y);
        ax = fmaf(v0, __uint_as_float(u0 << 16), ax);
        ay = fmaf(v0, __uint_as_float(u0 & 0xFFFF0000u), ay);
    }

    float2 b = *(const float2*)(bias + lane * 2);
    *(float2*)(out + (size_t)wave * OUT_F + lane * 2) = make_float2(ax + b.x, ay + b.y);
}

// -------------------- launch --------------------
extern "C" void kernel_launch(void* const* d_in, const int* in_sizes, int n_in,
                              void* d_out, int out_size, void* d_ws, size_t ws_size,
                              hipStream_t stream)
{
    const float* x     = (const float*)d_in[0];
    const int*   erow  = (const int*)d_in[1];
    const int*   ecol  = (const int*)d_in[2];
    const float* eval_ = (const float*)d_in[3];
    const float* w     = (const float*)d_in[4];
    const float* bias  = (const float*)d_in[5];
    float*       out   = (float*)d_out;

    // workspace layout (bytes):
    //   h (bf16):    0          .. 25,600,000
    //   tmp:         25,600,000 .. +25,600,000
    //   packed:      51,200,000 .. +25,600,000
    //   cntmat:      76,800,000 .. +800,768   (512 x 391 int)
    //   blockbase:   77,600,768 .. +800,768
    //   tot:         78,401,536 .. +1,568
    //   bucket_base: 78,403,104 .. +1,568
    //   row_start:   78,404,672 .. +400,000
    //   rowtot:      78,804,672 .. +400,000
    //   wbfF:        79,204,672 .. +65,536    (total ~79.3 MB)
    char* ws = (char*)d_ws;
    unsigned short* h           = (unsigned short*)(ws);
    int2*           tmp         = (int2*)(ws + 25600000);
    int2*           packed      = (int2*)(ws + 51200000);
    int*            cntmat      = (int*)(ws + 76800000);
    int*            blockbase   = (int*)(ws + 77600768);
    int*            tot         = (int*)(ws + 78401536);
    int*            bucket_base = (int*)(ws + 78403104);
    int*            row_start   = (int*)(ws + 78404672);
    int*            rowtot      = (int*)(ws + 78804672);
    uint4*          wbfF        = (uint4*)(ws + 79204672);

    // 0) w -> frag-ordered bf16
    hipLaunchKernelGGL(conv_w_kernel, dim3(16), dim3(256), 0, stream, w, wbfF);

    // 1) fused: h = bf16(x@w) via MFMA  ||  coarse histogram
    hipLaunchKernelGGL(gemm_hist_kernel, dim3(GEMM_BLOCKS + NBC), dim3(256), 0, stream,
                       x, wbfF, h, erow, cntmat);

    // 2) scans
    hipLaunchKernelGGL(pass_b_kernel, dim3(NBIN), dim3(256), 0, stream,
                       cntmat, blockbase, tot);
    hipLaunchKernelGGL(pass_b2_kernel, dim3(1), dim3(512), 0, stream, tot, bucket_base);

    // 3) scatter into bucket-ordered tmp
    hipLaunchKernelGGL(pass_c_kernel, dim3(NBC), dim3(256), 0, stream,
                       erow, ecol, eval_, blockbase, bucket_base, tmp);

    // 4) fine sort -> packed CSR
    hipLaunchKernelGGL(pass_d_kernel, dim3(NBIN), dim3(256), 0, stream,
                       tmp, bucket_base, packed, row_start, rowtot);

    // 5) aggregate rows + bias
    hipLaunchKernelGGL(aggregate_kernel,
                       dim3((N_NODES * 64 + 255) / 256), dim3(256), 0, stream,
                       packed, row_start, rowtot, (const unsigned*)h, bias, out);
}

// Round 10
// 216.887 us; speedup vs baseline: 11.1806x; 1.0937x over previous
//
#include <hip/hip_runtime.h>
#include <hip/hip_bf16.h>

#define N_NODES 100000
#define N_EDGES 3200000
#define IN_F 256
#define OUT_F 128

#define NBIN 391          // coarse bins: row >> 8  (99999>>8 = 390)
#define NBC  800          // coarse pass blocks
#define CHUNK 4000        // edges per coarse block (800*4000 = 3.2M exactly, %4==0)
#define GEMM_BLOCKS 782   // (N_NODES + 127) / 128

typedef __attribute__((ext_vector_type(8))) short bf16x8;
typedef __attribute__((ext_vector_type(4))) float f32x4;

union U4BF { uint4 u; bf16x8 v; };

// RNE f32->bf16 via HIP intrinsics: compiler can fuse pairs into v_cvt_pk_bf16_f32
__device__ inline unsigned short f2bf(float f) {
    return __bfloat16_as_ushort(__float2bfloat16(f));
}
__device__ inline unsigned pk2(float a, float b) {
    unsigned la = __bfloat16_as_ushort(__float2bfloat16(a));
    unsigned lb = __bfloat16_as_ushort(__float2bfloat16(b));
    return la | (lb << 16);
}

// -------------------- Kernel 0: w -> frag-ordered bf16 --------------------
__global__ __launch_bounds__(256) void conv_w_kernel(
    const float* __restrict__ w, uint4* __restrict__ wbfF)
{
    int tid = blockIdx.x * 256 + threadIdx.x;   // 0..4095
    int ks = tid >> 9;
    int fn = (tid >> 6) & 7;
    int l  = tid & 63;
    int c  = fn * 16 + (l & 15);
    int k0 = ks * 32 + (l >> 4) * 8;
    const float* wp = w + (size_t)k0 * OUT_F + c;
    uint4 u;
    u.x = pk2(wp[0 * OUT_F], wp[1 * OUT_F]);
    u.y = pk2(wp[2 * OUT_F], wp[3 * OUT_F]);
    u.z = pk2(wp[4 * OUT_F], wp[5 * OUT_F]);
    u.w = pk2(wp[6 * OUT_F], wp[7 * OUT_F]);
    wbfF[tid] = u;
}

// -------------------- Kernel 1: fused GEMM (blocks 0..781) + coarse hist (782..1581) ----
__global__ __launch_bounds__(256) void gemm_hist_kernel(
    const float* __restrict__ x, const uint4* __restrict__ wbfF,
    unsigned short* __restrict__ h,
    const int* __restrict__ erow, int* __restrict__ cntmat)
{
    __shared__ __align__(16) char smem[65536];
    const int t = threadIdx.x;

    if (blockIdx.x < GEMM_BLOCKS) {
        // ================= GEMM path =================
        uint4* bsh = (uint4*)smem;
        const int lane = t & 63;
        const int wid  = t >> 6;
        const int brow = blockIdx.x * 128;
        const int ln   = lane & 15;
        const int kb   = lane >> 4;

#pragma unroll
        for (int i = 0; i < 16; ++i) bsh[i * 256 + t] = wbfF[i * 256 + t];

        int r0 = brow + wid * 32 + ln;
        int r1 = r0 + 16;
        const float* a0p = x + (size_t)(r0 < N_NODES ? r0 : N_NODES - 1) * IN_F;
        const float* a1p = x + (size_t)(r1 < N_NODES ? r1 : N_NODES - 1) * IN_F;

        f32x4 acc[2][8] = {};
        __syncthreads();

#pragma unroll
        for (int ks = 0; ks < 8; ++ks) {
            const int k = ks * 32 + kb * 8;
            U4BF a0, a1;
            {
                float4 p = *(const float4*)(a0p + k);
                float4 q = *(const float4*)(a0p + k + 4);
                a0.u.x = pk2(p.x, p.y); a0.u.y = pk2(p.z, p.w);
                a0.u.z = pk2(q.x, q.y); a0.u.w = pk2(q.z, q.w);
            }
            {
                float4 p = *(const float4*)(a1p + k);
                float4 q = *(const float4*)(a1p + k + 4);
                a1.u.x = pk2(p.x, p.y); a1.u.y = pk2(p.z, p.w);
                a1.u.z = pk2(q.x, q.y); a1.u.w = pk2(q.z, q.w);
            }
            U4BF b[8];
#pragma unroll
            for (int fn = 0; fn < 8; ++fn)
                b[fn].u = bsh[(ks * 8 + fn) * 64 + lane];
#pragma unroll
            for (int fn = 0; fn < 8; ++fn) {
                acc[0][fn] = __builtin_amdgcn_mfma_f32_16x16x32_bf16(
                    a0.v, b[fn].v, acc[0][fn], 0, 0, 0);
                acc[1][fn] = __builtin_amdgcn_mfma_f32_16x16x32_bf16(
                    a1.v, b[fn].v, acc[1][fn], 0, 0, 0);
            }
        }

#pragma unroll
        for (int fm = 0; fm < 2; ++fm) {
#pragma unroll
            for (int r = 0; r < 4; ++r) {
                int grow = brow + wid * 32 + fm * 16 + (lane >> 4) * 4 + r;
                if (grow < N_NODES) {
                    unsigned short* dst = h + (size_t)grow * OUT_F + ln;
#pragma unroll
                    for (int fn = 0; fn < 8; ++fn)
                        dst[fn * 16] = f2bf(acc[fm][fn][r]);
                }
            }
        }
    } else {
        // ================= Pass A path: coarse LDS histogram =================
        int* lhist = (int*)smem;
        const int b = blockIdx.x - GEMM_BLOCKS;
        for (int i = t; i < NBIN; i += 256) lhist[i] = 0;
        __syncthreads();

        const int base = b * CHUNK;
        const int end  = min(base + CHUNK, N_EDGES);
        for (int i = base + t * 4; i < end; i += 1024) {
            int4 r = *(const int4*)(erow + i);
            atomicAdd(&lhist[r.x >> 8], 1);
            atomicAdd(&lhist[r.y >> 8], 1);
            atomicAdd(&lhist[r.z >> 8], 1);
            atomicAdd(&lhist[r.w >> 8], 1);
        }
        __syncthreads();

        int* dst = cntmat + (size_t)b * NBIN;
        for (int j = t; j < NBIN; j += 256) dst[j] = lhist[j];
    }
}

// -------------------- Pass B: per-bin exclusive scan over 800 blocks --------------------
// Thread t owns blocks 4t..4t+3 of column j.
__global__ __launch_bounds__(256) void pass_b_kernel(
    const int* __restrict__ cntmat, int* __restrict__ blockbase,
    int* __restrict__ tot)
{
    __shared__ int sh[256];
    const int t = threadIdx.x;
    const int j = blockIdx.x;
    int c[4];
    int ps = 0;
#pragma unroll
    for (int i = 0; i < 4; ++i) {
        int bb = 4 * t + i;
        c[i] = (bb < NBC) ? cntmat[(size_t)bb * NBIN + j] : 0;
        ps += c[i];
    }
    sh[t] = ps;
    __syncthreads();
    for (int off = 1; off < 256; off <<= 1) {
        int add = (t >= off) ? sh[t - off] : 0;
        __syncthreads();
        sh[t] += add;
        __syncthreads();
    }
    int excl = sh[t] - ps;
#pragma unroll
    for (int i = 0; i < 4; ++i) {
        int bb = 4 * t + i;
        if (bb < NBC) { blockbase[(size_t)bb * NBIN + j] = excl; excl += c[i]; }
    }
    if (t == 255) tot[j] = sh[255];
}

// -------------------- Pass B2: exclusive scan of bucket totals --------------------
__global__ __launch_bounds__(512) void pass_b2_kernel(
    const int* __restrict__ tot, int* __restrict__ bucket_base)
{
    __shared__ int sh[512];
    const int t = threadIdx.x;
    int v = (t < NBIN) ? tot[t] : 0;
    sh[t] = v;
    __syncthreads();
    for (int off = 1; off < 512; off <<= 1) {
        int add = (t >= off) ? sh[t - off] : 0;
        __syncthreads();
        sh[t] += add;
        __syncthreads();
    }
    if (t < NBIN + 1) bucket_base[t] = sh[t] - v;   // exclusive; [NBIN] = N_EDGES
}

// -------------------- Pass C v2: LDS counting-sort, coalesced write-out ----------
// Block sorts its CHUNK edges by bin in LDS, then writes bin-runs contiguously:
// global position = delta[bin] + local_sorted_pos, delta constant per run.
__global__ __launch_bounds__(256) void pass_c_kernel(
    const int* __restrict__ erow, const int* __restrict__ ecol,
    const float* __restrict__ eval_, const int* __restrict__ cntmat,
    const int* __restrict__ blockbase, const int* __restrict__ bucket_base,
    int2* __restrict__ tmp)
{
    __shared__ int2 skv[CHUNK];       // 32,000 B
    __shared__ int  sdelta[CHUNK];    // 16,000 B
    __shared__ int  cur[NBIN];
    __shared__ int  sdel[NBIN];
    __shared__ int  sscan[256];       // total ~52.2 KB -> 3 blocks/CU

    const int t = threadIdx.x;
    const int b = blockIdx.x;

    // local exclusive scan of this block's bin counts (2 bins/thread)
    int j0 = 2 * t, j1 = 2 * t + 1;
    int c0 = (j0 < NBIN) ? cntmat[(size_t)b * NBIN + j0] : 0;
    int c1 = (j1 < NBIN) ? cntmat[(size_t)b * NBIN + j1] : 0;
    int ps = c0 + c1;
    sscan[t] = ps;
    __syncthreads();
    for (int off = 1; off < 256; off <<= 1) {
        int add = (t >= off) ? sscan[t - off] : 0;
        __syncthreads();
        sscan[t] += add;
        __syncthreads();
    }
    int excl = sscan[t] - ps;
    if (j0 < NBIN) {
        cur[j0]  = excl;
        sdel[j0] = bucket_base[j0] + blockbase[(size_t)b * NBIN + j0] - excl;
    }
    if (j1 < NBIN) {
        cur[j1]  = excl + c0;
        sdel[j1] = bucket_base[j1] + blockbase[(size_t)b * NBIN + j1] - (excl + c0);
    }
    __syncthreads();

    // scatter into LDS by bin
    const int base = b * CHUNK;
    const int end  = min(base + CHUNK, N_EDGES);
    for (int i = base + t * 4; i < end; i += 1024) {
        int4   r = *(const int4*)(erow + i);
        int4   c = *(const int4*)(ecol + i);
        float4 v = *(const float4*)(eval_ + i);
        int bin, pos;
        bin = r.x >> 8; pos = atomicAdd(&cur[bin], 1);
        skv[pos] = make_int2(c.x | ((r.x & 255) << 17), __float_as_int(v.x));
        sdelta[pos] = sdel[bin];
        bin = r.y >> 8; pos = atomicAdd(&cur[bin], 1);
        skv[pos] = make_int2(c.y | ((r.y & 255) << 17), __float_as_int(v.y));
        sdelta[pos] = sdel[bin];
        bin = r.z >> 8; pos = atomicAdd(&cur[bin], 1);
        skv[pos] = make_int2(c.z | ((r.z & 255) << 17), __float_as_int(v.z));
        sdelta[pos] = sdel[bin];
        bin = r.w >> 8; pos = atomicAdd(&cur[bin], 1);
        skv[pos] = make_int2(c.w | ((r.w & 255) << 17), __float_as_int(v.w));
        sdelta[pos] = sdel[bin];
    }
    __syncthreads();

    // coalesced copy-out: consecutive i -> consecutive global within each run
    const int n = end - base;
    for (int i = t; i < n; i += 256) {
        int2 kv = skv[i];
        tmp[sdelta[i] + i] = kv;
    }
}

// -------------------- Pass D: fine sort within bucket -> CSR + row_start/rowtot ----
__global__ __launch_bounds__(256) void pass_d_kernel(
    const int2* __restrict__ tmp, const int* __restrict__ bucket_base,
    int2* __restrict__ packed, int* __restrict__ row_start,
    int* __restrict__ rowtot)
{
    __shared__ int hist[256];
    __shared__ int cursor[256];
    const int t = threadIdx.x;
    const int j = blockIdx.x;
    const int base = bucket_base[j];
    const int end  = bucket_base[j + 1];

    hist[t] = 0;
    __syncthreads();

    for (int i = base + t; i < end; i += 256)
        atomicAdd(&hist[tmp[i].x >> 17], 1);
    __syncthreads();

    int hv = hist[t];
    cursor[t] = hv;
    __syncthreads();
    for (int off = 1; off < 256; off <<= 1) {
        int add = (t >= off) ? cursor[t - off] : 0;
        __syncthreads();
        cursor[t] += add;
        __syncthreads();
    }
    int excl = cursor[t] - hv;

    int r = j * 256 + t;
    if (r < N_NODES) {
        row_start[r] = base + excl;
        rowtot[r]    = hv;
    }
    __syncthreads();
    cursor[t] = excl;
    __syncthreads();

    for (int i = base + t; i < end; i += 256) {
        int2 p = tmp[i];
        int rl = p.x >> 17;
        int pos = atomicAdd(&cursor[rl], 1);
        packed[base + pos] = make_int2(p.x & 0x1FFFF, p.y);
    }
}

// -------------------- Kernel 5: per-row gather-aggregate + bias --------------------
__global__ __launch_bounds__(256) void aggregate_kernel(
    const int2* __restrict__ packed, const int* __restrict__ row_start,
    const int* __restrict__ rowtot, const unsigned* __restrict__ h2,
    const float* __restrict__ bias, float* __restrict__ out)
{
    int wave = (blockIdx.x * 256 + threadIdx.x) >> 6;
    int lane = threadIdx.x & 63;
    if (wave >= N_NODES) return;

    int start = __builtin_amdgcn_readfirstlane(row_start[wave]);
    int deg   = __builtin_amdgcn_readfirstlane(rowtot[wave]);
    int end   = start + deg;

    const unsigned* hb = h2 + lane;
    float ax = 0.f, ay = 0.f;

    int e = start;
    for (; e + 7 < end; e += 8) {
        int2 p0 = packed[e];
        int2 p1 = packed[e + 1];
        int2 p2 = packed[e + 2];
        int2 p3 = packed[e + 3];
        int2 p4 = packed[e + 4];
        int2 p5 = packed[e + 5];
        int2 p6 = packed[e + 6];
        int2 p7 = packed[e + 7];
        unsigned u0 = hb[(size_t)p0.x << 6];
        unsigned u1 = hb[(size_t)p1.x << 6];
        unsigned u2 = hb[(size_t)p2.x << 6];
        unsigned u3 = hb[(size_t)p3.x << 6];
        unsigned u4 = hb[(size_t)p4.x << 6];
        unsigned u5 = hb[(size_t)p5.x << 6];
        unsigned u6 = hb[(size_t)p6.x << 6];
        unsigned u7 = hb[(size_t)p7.x << 6];
        float v0 = __int_as_float(p0.y), v1 = __int_as_float(p1.y);
        float v2 = __int_as_float(p2.y), v3 = __int_as_float(p3.y);
        float v4 = __int_as_float(p4.y), v5 = __int_as_float(p5.y);
        float v6 = __int_as_float(p6.y), v7 = __int_as_float(p7.y);
        ax = fmaf(v0, __uint_as_float(u0 << 16), ax);
        ay = fmaf(v0, __uint_as_float(u0 & 0xFFFF0000u), ay);
        ax = fmaf(v1, __uint_as_float(u1 << 16), ax);
        ay = fmaf(v1, __uint_as_float(u1 & 0xFFFF0000u), ay);
        ax = fmaf(v2, __uint_as_float(u2 << 16), ax);
        ay = fmaf(v2, __uint_as_float(u2 & 0xFFFF0000u), ay);
        ax = fmaf(v3, __uint_as_float(u3 << 16), ax);
        ay = fmaf(v3, __uint_as_float(u3 & 0xFFFF0000u), ay);
        ax = fmaf(v4, __uint_as_float(u4 << 16), ax);
        ay = fmaf(v4, __uint_as_float(u4 & 0xFFFF0000u), ay);
        ax = fmaf(v5, __uint_as_float(u5 << 16), ax);
        ay = fmaf(v5, __uint_as_float(u5 & 0xFFFF0000u), ay);
        ax = fmaf(v6, __uint_as_float(u6 << 16), ax);
        ay = fmaf(v6, __uint_as_float(u6 & 0xFFFF0000u), ay);
        ax = fmaf(v7, __uint_as_float(u7 << 16), ax);
        ay = fmaf(v7, __uint_as_float(u7 & 0xFFFF0000u), ay);
    }
    for (; e < end; ++e) {
        int2 p0 = packed[e];
        unsigned u0 = hb[(size_t)p0.x << 6];
        float v0 = __int_as_float(p0.y);
        ax = fmaf(v0, __uint_as_float(u0 << 16), ax);
        ay = fmaf(v0, __uint_as_float(u0 & 0xFFFF0000u), ay);
    }

    float2 b = *(const float2*)(bias + lane * 2);
    *(float2*)(out + (size_t)wave * OUT_F + lane * 2) = make_float2(ax + b.x, ay + b.y);
}

// -------------------- launch --------------------
extern "C" void kernel_launch(void* const* d_in, const int* in_sizes, int n_in,
                              void* d_out, int out_size, void* d_ws, size_t ws_size,
                              hipStream_t stream)
{
    const float* x     = (const float*)d_in[0];
    const int*   erow  = (const int*)d_in[1];
    const int*   ecol  = (const int*)d_in[2];
    const float* eval_ = (const float*)d_in[3];
    const float* w     = (const float*)d_in[4];
    const float* bias  = (const float*)d_in[5];
    float*       out   = (float*)d_out;

    // workspace layout (bytes):
    //   h (bf16):    0          .. 25,600,000
    //   tmp:         25,600,000 .. 51,200,000
    //   packed:      51,200,000 .. 76,800,000
    //   cntmat:      76,800,000 .. 78,051,200   (800 x 391 int)
    //   blockbase:   78,051,200 .. 79,302,400
    //   tot:         79,302,400 .. 79,303,968
    //   bucket_base: 79,303,968 .. 79,305,536   (392 int)
    //   row_start:   79,305,536 .. 79,705,536
    //   rowtot:      79,705,536 .. 80,105,536
    //   wbfF:        80,105,536 .. 80,171,072   (~80.2 MB)
    char* ws = (char*)d_ws;
    unsigned short* h           = (unsigned short*)(ws);
    int2*           tmp         = (int2*)(ws + 25600000);
    int2*           packed      = (int2*)(ws + 51200000);
    int*            cntmat      = (int*)(ws + 76800000);
    int*            blockbase   = (int*)(ws + 78051200);
    int*            tot         = (int*)(ws + 79302400);
    int*            bucket_base = (int*)(ws + 79303968);
    int*            row_start   = (int*)(ws + 79305536);
    int*            rowtot      = (int*)(ws + 79705536);
    uint4*          wbfF        = (uint4*)(ws + 80105536);

    // 0) w -> frag-ordered bf16
    hipLaunchKernelGGL(conv_w_kernel, dim3(16), dim3(256), 0, stream, w, wbfF);

    // 1) fused: h = bf16(x@w) via MFMA  ||  coarse histogram
    hipLaunchKernelGGL(gemm_hist_kernel, dim3(GEMM_BLOCKS + NBC), dim3(256), 0, stream,
                       x, wbfF, h, erow, cntmat);

    // 2) scans
    hipLaunchKernelGGL(pass_b_kernel, dim3(NBIN), dim3(256), 0, stream,
                       cntmat, blockbase, tot);
    hipLaunchKernelGGL(pass_b2_kernel, dim3(1), dim3(512), 0, stream, tot, bucket_base);

    // 3) LDS counting-sort scatter into bucket-ordered tmp (coalesced writes)
    hipLaunchKernelGGL(pass_c_kernel, dim3(NBC), dim3(256), 0, stream,
                       erow, ecol, eval_, cntmat, blockbase, bucket_base, tmp);

    // 4) fine sort -> packed CSR
    hipLaunchKernelGGL(pass_d_kernel, dim3(NBIN), dim3(256), 0, stream,
                       tmp, bucket_base, packed, row_start, rowtot);

    // 5) aggregate rows + bias
    hipLaunchKernelGGL(aggregate_kernel,
                       dim3((N_NODES * 64 + 255) / 256), dim3(256), 0, stream,
                       packed, row_start, rowtot, (const unsigned*)h, bias, out);
}